// Round 10
// baseline (134.952 us; speedup 1.0000x reference)
//
#include <hip/hip_runtime.h>
#include <math.h>

#define BB 8
#define NN 64
#define SS 128
#define DD 512
#define HH 8
#define DKK 64
#define NSENT (BB * NN)          // 512
#define NTOK  (NSENT * SS)       // 65536
#define SENT_STRIDE (SS * DD)    // 65536 floats per sentence of x / out

// d_ws layout (floats). z aliases w (w is dead once kx finishes).
#define WK_OFF 0                          // wk_t[8][512]           (16 KB)
#define W_OFF  4096                       // w[65536][8]            (2 MB)
#define Z_OFF  4096                       // z[512][512]  (aliases w, 1 MB)
#define XB_OFF (W_OFF + NTOK * HH)        // xbar[512][8][512]      (8 MB)

// ---------------------------------------------------------------------------
// DPP / swizzle helpers (imm operands must be ICE -> template params)
// ---------------------------------------------------------------------------
template <int CTRL>
__device__ __forceinline__ float ror_add(float v) {
    int r = __builtin_amdgcn_update_dpp(0, __float_as_int(v), CTRL, 0xf, 0xf, true);
    return v + __int_as_float(r);
}
// allreduce over each 16-lane row via rotate-by-1/2/4/8 (VALU pipe, no LDS)
__device__ __forceinline__ float row_allreduce(float v) {
    v = ror_add<0x121>(v);   // row_ror:1
    v = ror_add<0x122>(v);   // row_ror:2
    v = ror_add<0x124>(v);   // row_ror:4
    v = ror_add<0x128>(v);   // row_ror:8
    return v;
}

// ---------------------------------------------------------------------------
// K0: fold Wk with sent_q: wk_t[h][d] = sum_k Wk[d, h*64+k] * sent_q[h,k]
// (bk is softmax-shift-invariant; Wq/bq dead: token softmax is over a singleton)
// ---------------------------------------------------------------------------
__global__ void precompute_wk(const float* __restrict__ Wk,
                              const float* __restrict__ sq,
                              float* __restrict__ wk_t) {
    const int d = threadIdx.x;
    const int h = blockIdx.x;
    const float4* wrow = (const float4*)(Wk + (size_t)d * DD + h * DKK);
    const float4* sqv  = (const float4*)(sq + h * DKK);
    float acc = 0.f;
#pragma unroll
    for (int k = 0; k < DKK / 4; ++k) {
        float4 w = wrow[k], q = sqv[k];
        acc += w.x * q.x + w.y * q.y + w.z * q.z + w.w * q.w;
    }
    wk_t[h * DD + d] = acc;
}

// ---------------------------------------------------------------------------
// KS: exp-weights, maximal memory-level parallelism. Wave = 2 tokens, block =
// 8 tokens, 8192 blocks. All 8 x-loads independent and issued up front; short
// DPP reduce; 64B store w[tok][h]. High occupancy + block churn keeps ~30KB
// of loads in flight per CU.
// ---------------------------------------------------------------------------
__global__ __launch_bounds__(256, 4)
void ks_scores(const float* __restrict__ x, const int* __restrict__ mask,
               const float* __restrict__ wk_t, float* __restrict__ w)
{
    const int t    = threadIdx.x;
    const int wave = t >> 6;
    const int lane = t & 63;
    const int d0   = lane * 8;
    const int tok0 = blockIdx.x * 8 + wave * 2;

    // x loads first: 4 independent float4s in flight while wk loads (L2-hot)
    const float* xp = x + (size_t)tok0 * DD + d0;
    const float4 a0 = *(const float4*)(xp);
    const float4 b0 = *(const float4*)(xp + 4);
    const float4 a1 = *(const float4*)(xp + DD);
    const float4 b1 = *(const float4*)(xp + DD + 4);

    float4 wkA[HH], wkB[HH];
#pragma unroll
    for (int h = 0; h < HH; ++h) {
        wkA[h] = *(const float4*)(wk_t + h * DD + d0);
        wkB[h] = *(const float4*)(wk_t + h * DD + d0 + 4);
    }
    const int m0 = mask[tok0];
    const int m1 = mask[tok0 + 1];

    float p0[HH], p1[HH];
#pragma unroll
    for (int h = 0; h < HH; ++h) {
        p0[h] = a0.x * wkA[h].x + a0.y * wkA[h].y + a0.z * wkA[h].z + a0.w * wkA[h].w
              + b0.x * wkB[h].x + b0.y * wkB[h].y + b0.z * wkB[h].z + b0.w * wkB[h].w;
        p1[h] = a1.x * wkA[h].x + a1.y * wkA[h].y + a1.z * wkA[h].z + a1.w * wkA[h].w
              + b1.x * wkB[h].x + b1.y * wkB[h].y + b1.z * wkB[h].z + b1.w * wkB[h].w;
    }
#pragma unroll
    for (int h = 0; h < HH; ++h) {
        p0[h] = row_allreduce(p0[h]);
        p1[h] = row_allreduce(p1[h]);
    }
    const int r = lane & 7;
    float v0 = p0[0], v1 = p1[0];
#pragma unroll
    for (int h = 1; h < HH; ++h) {
        v0 = (r == h) ? p0[h] : v0;
        v1 = (r == h) ? p1[h] : v1;
    }
    v0 += __shfl_xor(v0, 16, 64);
    v0 += __shfl_xor(v0, 32, 64);
    v1 += __shfl_xor(v1, 16, 64);
    v1 += __shfl_xor(v1, 32, 64);

    const float e0 = m0 ? __expf(v0 * 0.125f) : 0.f;
    const float e1 = m1 ? __expf(v1 * 0.125f) : 0.f;

    // lanes 0-7 store token0's 8 heads; lanes 8-15 store token1's (64B dense)
    if (lane < 16) {
        const float e = (lane < 8) ? e0 : e1;
        w[(size_t)tok0 * HH + lane] = e;
    }
}

// ---------------------------------------------------------------------------
// KX: xbar[sent][h][d] = sum_s w[s][h]*x[s][d] / sum_s w[s][h].
// Block = (sent, quarter of dims), 128 thr, thread owns one dim.
// w staged in 4KB LDS (uniform broadcast reads); x reads 8-deep prefetched
// (LLC-hot after KS); per-head wsum accumulated redundantly per thread.
// ---------------------------------------------------------------------------
__global__ __launch_bounds__(128, 8)
void kx_xbar(const float* __restrict__ x, const float* __restrict__ w,
             float* __restrict__ xbar)
{
    __shared__ float wl[SS][HH];   // 4 KB

    const int bid  = blockIdx.x;
    const int sent = bid >> 2, q = bid & 3;
    const int t    = threadIdx.x;

    // stage w[sent][s][h]: thread t loads row s=t (8 floats, 32B aligned)
    {
        const float4* wp = (const float4*)(w + (size_t)sent * SS * HH);
        const float4 w0 = wp[t * 2];
        const float4 w1 = wp[t * 2 + 1];
        *(float4*)&wl[t][0] = w0;
        *(float4*)&wl[t][4] = w1;
    }
    __syncthreads();

    const int d = q * 128 + t;
    const float* xp = x + (size_t)sent * SENT_STRIDE + d;

    float acc[HH], wsum[HH];
#pragma unroll
    for (int h = 0; h < HH; ++h) { acc[h] = 0.f; wsum[h] = 0.f; }

    float xa[8], xb[8];
#pragma unroll
    for (int j = 0; j < 8; ++j) xa[j] = xp[(size_t)j * DD];

    for (int s0 = 0; s0 < SS; s0 += 16) {
#pragma unroll
        for (int j = 0; j < 8; ++j) xb[j] = xp[(size_t)(s0 + 8 + j) * DD];
#pragma unroll
        for (int j = 0; j < 8; ++j) {
            const float4 w0 = *(const float4*)&wl[s0 + j][0];
            const float4 w1 = *(const float4*)&wl[s0 + j][4];
            const float xv = xa[j];
            acc[0] += w0.x * xv; acc[1] += w0.y * xv;
            acc[2] += w0.z * xv; acc[3] += w0.w * xv;
            acc[4] += w1.x * xv; acc[5] += w1.y * xv;
            acc[6] += w1.z * xv; acc[7] += w1.w * xv;
            wsum[0] += w0.x; wsum[1] += w0.y; wsum[2] += w0.z; wsum[3] += w0.w;
            wsum[4] += w1.x; wsum[5] += w1.y; wsum[6] += w1.z; wsum[7] += w1.w;
        }
        if (s0 + 16 < SS) {
#pragma unroll
            for (int j = 0; j < 8; ++j) xa[j] = xp[(size_t)(s0 + 16 + j) * DD];
        }
#pragma unroll
        for (int j = 0; j < 8; ++j) {
            const float4 w0 = *(const float4*)&wl[s0 + 8 + j][0];
            const float4 w1 = *(const float4*)&wl[s0 + 8 + j][4];
            const float xv = xb[j];
            acc[0] += w0.x * xv; acc[1] += w0.y * xv;
            acc[2] += w0.z * xv; acc[3] += w0.w * xv;
            acc[4] += w1.x * xv; acc[5] += w1.y * xv;
            acc[6] += w1.z * xv; acc[7] += w1.w * xv;
            wsum[0] += w0.x; wsum[1] += w0.y; wsum[2] += w0.z; wsum[3] += w0.w;
            wsum[4] += w1.x; wsum[5] += w1.y; wsum[6] += w1.z; wsum[7] += w1.w;
        }
    }

    float* xbp = xbar + (size_t)sent * (HH * DD) + d;
#pragma unroll
    for (int h = 0; h < HH; ++h)
        xbp[h * DD] = acc[h] / wsum[h];
}

// ---------------------------------------------------------------------------
// KZ: 16x64-tile fp32 GEMM (register-prefetched), 256 blocks.
// A=xbar (am=4096, a_nb=512 head select), B=Wv, bias=bv -> z
// ---------------------------------------------------------------------------
__global__ __launch_bounds__(256)
void gemm_tile(const float* __restrict__ A, const int am_stride, const int a_nb_stride,
               const float* __restrict__ B, const float* __restrict__ bias,
               float* __restrict__ C)
{
    __shared__ float As[64][17];   // [k][m]
    __shared__ float Bs[64][68];   // [k][n]

    const int nb = blockIdx.x & 7, mb = blockIdx.x >> 3;
    const int t  = threadIdx.x;
    const int tr = t >> 4, tc = t & 15;

    const float* Ab = A + (size_t)(mb * 16) * am_stride + nb * a_nb_stride
                        + (size_t)tr * am_stride + tc * 4;
    const float* Bb = B + nb * 64 + (size_t)tr * DD + tc * 4;

    float4 ar = *(const float4*)(Ab);
    float4 br0 = *(const float4*)(Bb);
    float4 br1 = *(const float4*)(Bb + 16 * DD);
    float4 br2 = *(const float4*)(Bb + 32 * DD);
    float4 br3 = *(const float4*)(Bb + 48 * DD);

    float a0 = 0.f, a1 = 0.f, a2 = 0.f, a3 = 0.f;

    for (int k0 = 0; k0 < DD; k0 += 64) {
        As[tc * 4 + 0][tr] = ar.x;
        As[tc * 4 + 1][tr] = ar.y;
        As[tc * 4 + 2][tr] = ar.z;
        As[tc * 4 + 3][tr] = ar.w;
        *(float4*)&Bs[tr +  0][tc * 4] = br0;
        *(float4*)&Bs[tr + 16][tc * 4] = br1;
        *(float4*)&Bs[tr + 32][tc * 4] = br2;
        *(float4*)&Bs[tr + 48][tc * 4] = br3;
        __syncthreads();
        if (k0 + 64 < DD) {       // prefetch next K-tile; overlaps compute below
            ar  = *(const float4*)(Ab + k0 + 64);
            br0 = *(const float4*)(Bb + (size_t)(k0 + 64) * DD);
            br1 = *(const float4*)(Bb + (size_t)(k0 + 80) * DD);
            br2 = *(const float4*)(Bb + (size_t)(k0 + 96) * DD);
            br3 = *(const float4*)(Bb + (size_t)(k0 + 112) * DD);
        }
#pragma unroll
        for (int kk = 0; kk < 64; ++kk) {
            const float av = As[kk][tr];
            const float4 bv4 = *(const float4*)&Bs[kk][tc * 4];
            a0 += av * bv4.x; a1 += av * bv4.y; a2 += av * bv4.z; a3 += av * bv4.w;
        }
        __syncthreads();
    }

    const float4 bb = *(const float4*)(bias + nb * 64 + tc * 4);
    float4 o; o.x = a0 + bb.x; o.y = a1 + bb.y; o.z = a2 + bb.z; o.w = a3 + bb.w;
    *(float4*)(C + (size_t)(mb * 16 + tr) * DD + nb * 64 + tc * 4) = o;
}

// ---------------------------------------------------------------------------
// KYB: final projection GEMM (A=z, B=Wo) FUSED with the token broadcast:
// each thread writes its y float4 to all 128 token rows of its sentence.
// ---------------------------------------------------------------------------
__global__ __launch_bounds__(256)
void kyb_proj_bcast(const float* __restrict__ z, const float* __restrict__ Wo,
                    const float* __restrict__ bo, float* __restrict__ outp)
{
    __shared__ float As[64][17];
    __shared__ float Bs[64][68];

    const int nb = blockIdx.x & 7, mb = blockIdx.x >> 3;
    const int t  = threadIdx.x;
    const int tr = t >> 4, tc = t & 15;

    const float* Ab = z + (size_t)(mb * 16 + tr) * DD + tc * 4;
    const float* Bb = Wo + nb * 64 + (size_t)tr * DD + tc * 4;

    float4 ar = *(const float4*)(Ab);
    float4 br0 = *(const float4*)(Bb);
    float4 br1 = *(const float4*)(Bb + 16 * DD);
    float4 br2 = *(const float4*)(Bb + 32 * DD);
    float4 br3 = *(const float4*)(Bb + 48 * DD);

    float a0 = 0.f, a1 = 0.f, a2 = 0.f, a3 = 0.f;

    for (int k0 = 0; k0 < DD; k0 += 64) {
        As[tc * 4 + 0][tr] = ar.x;
        As[tc * 4 + 1][tr] = ar.y;
        As[tc * 4 + 2][tr] = ar.z;
        As[tc * 4 + 3][tr] = ar.w;
        *(float4*)&Bs[tr +  0][tc * 4] = br0;
        *(float4*)&Bs[tr + 16][tc * 4] = br1;
        *(float4*)&Bs[tr + 32][tc * 4] = br2;
        *(float4*)&Bs[tr + 48][tc * 4] = br3;
        __syncthreads();
        if (k0 + 64 < DD) {
            ar  = *(const float4*)(Ab + k0 + 64);
            br0 = *(const float4*)(Bb + (size_t)(k0 + 64) * DD);
            br1 = *(const float4*)(Bb + (size_t)(k0 + 80) * DD);
            br2 = *(const float4*)(Bb + (size_t)(k0 + 96) * DD);
            br3 = *(const float4*)(Bb + (size_t)(k0 + 112) * DD);
        }
#pragma unroll
        for (int kk = 0; kk < 64; ++kk) {
            const float av = As[kk][tr];
            const float4 bv4 = *(const float4*)&Bs[kk][tc * 4];
            a0 += av * bv4.x; a1 += av * bv4.y; a2 += av * bv4.z; a3 += av * bv4.w;
        }
        __syncthreads();
    }

    const float4 bb = *(const float4*)(bo + nb * 64 + tc * 4);
    float4 o; o.x = a0 + bb.x; o.y = a1 + bb.y; o.z = a2 + bb.z; o.w = a3 + bb.w;

    // broadcast: identical row value for every token of this sentence
    const int sent = mb * 16 + tr;
    float* op = outp + (size_t)sent * SENT_STRIDE + nb * 64 + tc * 4;
#pragma unroll 8
    for (int s = 0; s < SS; ++s)
        *(float4*)(op + (size_t)s * DD) = o;
}

extern "C" void kernel_launch(void* const* d_in, const int* in_sizes, int n_in,
                              void* d_out, int out_size, void* d_ws, size_t ws_size,
                              hipStream_t stream) {
    const float* x    = (const float*)d_in[0];
    const int*   mask = (const int*)  d_in[1];
    // d_in[2]=Wq, d_in[3]=bq dead (token softmax over singleton); d_in[5]=bk shift-invariant
    const float* Wk   = (const float*)d_in[4];
    const float* Wv   = (const float*)d_in[6];
    const float* bv   = (const float*)d_in[7];
    const float* sq   = (const float*)d_in[8];
    const float* Wo   = (const float*)d_in[9];
    const float* bo   = (const float*)d_in[10];
    float* out = (float*)d_out;
    float* ws  = (float*)d_ws;

    float* wk_t = ws + WK_OFF;
    float* w    = ws + W_OFF;
    float* xbar = ws + XB_OFF;
    float* z    = ws + Z_OFF;    // aliases w (w dead after kx_xbar)

    precompute_wk<<<HH, DD, 0, stream>>>(Wk, sq, wk_t);
    ks_scores<<<NTOK / 8, 256, 0, stream>>>(x, mask, wk_t, w);
    kx_xbar<<<NSENT * 4, 128, 0, stream>>>(x, w, xbar);
    gemm_tile<<<256, 256, 0, stream>>>(xbar, HH * DD, DD, Wv, bv, z);
    kyb_proj_bcast<<<256, 256, 0, stream>>>(z, Wo, bo, out);
}

// Round 11
// 111.796 us; speedup vs baseline: 1.2071x; 1.2071x over previous
//
#include <hip/hip_runtime.h>
#include <math.h>

#define BB 8
#define NN 64
#define SS 128
#define DD 512
#define HH 8
#define DKK 64
#define NSENT (BB * NN)          // 512
#define NTOK  (NSENT * SS)       // 65536
#define SENT_STRIDE (SS * DD)    // 65536 floats per sentence of x / out

// d_ws layout (floats); ws is large (harness fills show ~512MB), total 12.6MB
#define WK_OFF 0                          // wk_t[8][512]        (16 KB)
#define W_OFF  4096                       // w[65536][8]         (2 MB)
#define XB_OFF (W_OFF + NTOK * HH)        // xbar[512][8][512]   (8 MB)
#define Z_OFF  (XB_OFF + NSENT * HH * DD) // z[512][512]         (1 MB)
#define YY_OFF (Z_OFF + NSENT * DD)       // y[512][512]         (1 MB)

// ---------------------------------------------------------------------------
// DPP helpers (imm operands must be ICE -> template params)
// ---------------------------------------------------------------------------
template <int CTRL>
__device__ __forceinline__ float ror_add(float v) {
    int r = __builtin_amdgcn_update_dpp(0, __float_as_int(v), CTRL, 0xf, 0xf, true);
    return v + __int_as_float(r);
}
// allreduce over each 16-lane row via rotate-by-1/2/4/8 (VALU pipe, no LDS)
__device__ __forceinline__ float row_allreduce(float v) {
    v = ror_add<0x121>(v);   // row_ror:1
    v = ror_add<0x122>(v);   // row_ror:2
    v = ror_add<0x124>(v);   // row_ror:4
    v = ror_add<0x128>(v);   // row_ror:8
    return v;
}

// ---------------------------------------------------------------------------
// K0: fold Wk with sent_q: wk_t[h][d] = sum_k Wk[d, h*64+k] * sent_q[h,k]
// (bk is softmax-shift-invariant; Wq/bq dead: token softmax is over a singleton)
// ---------------------------------------------------------------------------
__global__ void precompute_wk(const float* __restrict__ Wk,
                              const float* __restrict__ sq,
                              float* __restrict__ wk_t) {
    const int d = threadIdx.x;
    const int h = blockIdx.x;
    const float4* wrow = (const float4*)(Wk + (size_t)d * DD + h * DKK);
    const float4* sqv  = (const float4*)(sq + h * DKK);
    float acc = 0.f;
#pragma unroll
    for (int k = 0; k < DKK / 4; ++k) {
        float4 w = wrow[k], q = sqv[k];
        acc += w.x * q.x + w.y * q.y + w.z * q.z + w.w * q.w;
    }
    wk_t[h * DD + d] = acc;
}

// ---------------------------------------------------------------------------
// KS: exp-weights, maximal MLP. Wave = 2 tokens, block = 8 tokens, 8192
// blocks. All x-loads independent, issued up front; DPP reduce (VALU pipe);
// 64B store of w[tok][h].
// ---------------------------------------------------------------------------
__global__ __launch_bounds__(256, 4)
void ks_scores(const float* __restrict__ x, const int* __restrict__ mask,
               const float* __restrict__ wk_t, float* __restrict__ w)
{
    const int t    = threadIdx.x;
    const int wave = t >> 6;
    const int lane = t & 63;
    const int d0   = lane * 8;
    const int tok0 = blockIdx.x * 8 + wave * 2;

    // x loads first: 4 independent float4s in flight while wk loads (L1/L2-hot)
    const float* xp = x + (size_t)tok0 * DD + d0;
    const float4 a0 = *(const float4*)(xp);
    const float4 b0 = *(const float4*)(xp + 4);
    const float4 a1 = *(const float4*)(xp + DD);
    const float4 b1 = *(const float4*)(xp + DD + 4);

    float4 wkA[HH], wkB[HH];
#pragma unroll
    for (int h = 0; h < HH; ++h) {
        wkA[h] = *(const float4*)(wk_t + h * DD + d0);
        wkB[h] = *(const float4*)(wk_t + h * DD + d0 + 4);
    }
    const int m0 = mask[tok0];
    const int m1 = mask[tok0 + 1];

    float p0[HH], p1[HH];
#pragma unroll
    for (int h = 0; h < HH; ++h) {
        p0[h] = a0.x * wkA[h].x + a0.y * wkA[h].y + a0.z * wkA[h].z + a0.w * wkA[h].w
              + b0.x * wkB[h].x + b0.y * wkB[h].y + b0.z * wkB[h].z + b0.w * wkB[h].w;
        p1[h] = a1.x * wkA[h].x + a1.y * wkA[h].y + a1.z * wkA[h].z + a1.w * wkA[h].w
              + b1.x * wkB[h].x + b1.y * wkB[h].y + b1.z * wkB[h].z + b1.w * wkB[h].w;
    }
#pragma unroll
    for (int h = 0; h < HH; ++h) {
        p0[h] = row_allreduce(p0[h]);
        p1[h] = row_allreduce(p1[h]);
    }
    const int r = lane & 7;
    float v0 = p0[0], v1 = p1[0];
#pragma unroll
    for (int h = 1; h < HH; ++h) {
        v0 = (r == h) ? p0[h] : v0;
        v1 = (r == h) ? p1[h] : v1;
    }
    v0 += __shfl_xor(v0, 16, 64);
    v0 += __shfl_xor(v0, 32, 64);
    v1 += __shfl_xor(v1, 16, 64);
    v1 += __shfl_xor(v1, 32, 64);

    const float e0 = m0 ? __expf(v0 * 0.125f) : 0.f;
    const float e1 = m1 ? __expf(v1 * 0.125f) : 0.f;

    // lanes 0-7 store token0's 8 heads; lanes 8-15 store token1's (64B dense)
    if (lane < 16) {
        const float e = (lane < 8) ? e0 : e1;
        w[(size_t)tok0 * HH + lane] = e;
    }
}

// ---------------------------------------------------------------------------
// KX: xbar[sent][h][d] = sum_s w[s][h]*x[s][d] / sum_s w[s][h].
// Block = (sent, quarter of dims), 128 thr, thread owns one dim.
// w staged in 4KB LDS (uniform broadcast reads); x reads 8-deep prefetched
// (LLC-hot after KS); per-head wsum accumulated redundantly per thread.
// ---------------------------------------------------------------------------
__global__ __launch_bounds__(128, 8)
void kx_xbar(const float* __restrict__ x, const float* __restrict__ w,
             float* __restrict__ xbar)
{
    __shared__ float wl[SS][HH];   // 4 KB

    const int bid  = blockIdx.x;
    const int sent = bid >> 2, q = bid & 3;
    const int t    = threadIdx.x;

    // stage w[sent][s][h]: thread t loads row s=t (8 floats, 32B aligned)
    {
        const float4* wp = (const float4*)(w + (size_t)sent * SS * HH);
        const float4 w0 = wp[t * 2];
        const float4 w1 = wp[t * 2 + 1];
        *(float4*)&wl[t][0] = w0;
        *(float4*)&wl[t][4] = w1;
    }
    __syncthreads();

    const int d = q * 128 + t;
    const float* xp = x + (size_t)sent * SENT_STRIDE + d;

    float acc[HH], wsum[HH];
#pragma unroll
    for (int h = 0; h < HH; ++h) { acc[h] = 0.f; wsum[h] = 0.f; }

    float xa[8], xb[8];
#pragma unroll
    for (int j = 0; j < 8; ++j) xa[j] = xp[(size_t)j * DD];

    for (int s0 = 0; s0 < SS; s0 += 16) {
#pragma unroll
        for (int j = 0; j < 8; ++j) xb[j] = xp[(size_t)(s0 + 8 + j) * DD];
#pragma unroll
        for (int j = 0; j < 8; ++j) {
            const float4 w0 = *(const float4*)&wl[s0 + j][0];
            const float4 w1 = *(const float4*)&wl[s0 + j][4];
            const float xv = xa[j];
            acc[0] += w0.x * xv; acc[1] += w0.y * xv;
            acc[2] += w0.z * xv; acc[3] += w0.w * xv;
            acc[4] += w1.x * xv; acc[5] += w1.y * xv;
            acc[6] += w1.z * xv; acc[7] += w1.w * xv;
            wsum[0] += w0.x; wsum[1] += w0.y; wsum[2] += w0.z; wsum[3] += w0.w;
            wsum[4] += w1.x; wsum[5] += w1.y; wsum[6] += w1.z; wsum[7] += w1.w;
        }
        if (s0 + 16 < SS) {
#pragma unroll
            for (int j = 0; j < 8; ++j) xa[j] = xp[(size_t)(s0 + 16 + j) * DD];
        }
#pragma unroll
        for (int j = 0; j < 8; ++j) {
            const float4 w0 = *(const float4*)&wl[s0 + 8 + j][0];
            const float4 w1 = *(const float4*)&wl[s0 + 8 + j][4];
            const float xv = xb[j];
            acc[0] += w0.x * xv; acc[1] += w0.y * xv;
            acc[2] += w0.z * xv; acc[3] += w0.w * xv;
            acc[4] += w1.x * xv; acc[5] += w1.y * xv;
            acc[6] += w1.z * xv; acc[7] += w1.w * xv;
            wsum[0] += w0.x; wsum[1] += w0.y; wsum[2] += w0.z; wsum[3] += w0.w;
            wsum[4] += w1.x; wsum[5] += w1.y; wsum[6] += w1.z; wsum[7] += w1.w;
        }
    }

    float* xbp = xbar + (size_t)sent * (HH * DD) + d;
#pragma unroll
    for (int h = 0; h < HH; ++h)
        xbp[h * DD] = acc[h] / wsum[h];
}

// ---------------------------------------------------------------------------
// KZ/KY: 16x64-tile fp32 GEMM, register-prefetched across the barrier,
// 256 blocks (proven R8).
//  KZ: A=xbar (am=4096, a_nb=512 head select), B=Wv, bias=bv -> z
//  KY: A=z    (am=512,  a_nb=0),               B=Wo, bias=bo -> y
// ---------------------------------------------------------------------------
__global__ __launch_bounds__(256)
void gemm_tile(const float* __restrict__ A, const int am_stride, const int a_nb_stride,
               const float* __restrict__ B, const float* __restrict__ bias,
               float* __restrict__ C)
{
    __shared__ float As[64][17];   // [k][m]
    __shared__ float Bs[64][68];   // [k][n]

    const int nb = blockIdx.x & 7, mb = blockIdx.x >> 3;
    const int t  = threadIdx.x;
    const int tr = t >> 4, tc = t & 15;

    const float* Ab = A + (size_t)(mb * 16) * am_stride + nb * a_nb_stride
                        + (size_t)tr * am_stride + tc * 4;
    const float* Bb = B + nb * 64 + (size_t)tr * DD + tc * 4;

    float4 ar = *(const float4*)(Ab);
    float4 br0 = *(const float4*)(Bb);
    float4 br1 = *(const float4*)(Bb + 16 * DD);
    float4 br2 = *(const float4*)(Bb + 32 * DD);
    float4 br3 = *(const float4*)(Bb + 48 * DD);

    float a0 = 0.f, a1 = 0.f, a2 = 0.f, a3 = 0.f;

    for (int k0 = 0; k0 < DD; k0 += 64) {
        As[tc * 4 + 0][tr] = ar.x;
        As[tc * 4 + 1][tr] = ar.y;
        As[tc * 4 + 2][tr] = ar.z;
        As[tc * 4 + 3][tr] = ar.w;
        *(float4*)&Bs[tr +  0][tc * 4] = br0;
        *(float4*)&Bs[tr + 16][tc * 4] = br1;
        *(float4*)&Bs[tr + 32][tc * 4] = br2;
        *(float4*)&Bs[tr + 48][tc * 4] = br3;
        __syncthreads();
        if (k0 + 64 < DD) {       // prefetch next K-tile; overlaps compute below
            ar  = *(const float4*)(Ab + k0 + 64);
            br0 = *(const float4*)(Bb + (size_t)(k0 + 64) * DD);
            br1 = *(const float4*)(Bb + (size_t)(k0 + 80) * DD);
            br2 = *(const float4*)(Bb + (size_t)(k0 + 96) * DD);
            br3 = *(const float4*)(Bb + (size_t)(k0 + 112) * DD);
        }
#pragma unroll
        for (int kk = 0; kk < 64; ++kk) {
            const float av = As[kk][tr];
            const float4 bv4 = *(const float4*)&Bs[kk][tc * 4];
            a0 += av * bv4.x; a1 += av * bv4.y; a2 += av * bv4.z; a3 += av * bv4.w;
        }
        __syncthreads();
    }

    const float4 bb = *(const float4*)(bias + nb * 64 + tc * 4);
    float4 o; o.x = a0 + bb.x; o.y = a1 + bb.y; o.z = a2 + bb.z; o.w = a3 + bb.w;
    *(float4*)(C + (size_t)(mb * 16 + tr) * DD + nb * 64 + tc * 4) = o;
}

// ---------------------------------------------------------------------------
// KB: broadcast y[sent] to all 128 token rows of out. 2048 blocks x 256 thr.
// Wave-stores are 1KB contiguous (proven-fast write pattern).
// ---------------------------------------------------------------------------
__global__ __launch_bounds__(256)
void kb_bcast(const float* __restrict__ y, float* __restrict__ outp)
{
    const int sent = blockIdx.x >> 2, q = blockIdx.x & 3;
    const int c4 = threadIdx.x & 127;       // float4 column 0..127
    const int rr = threadIdx.x >> 7;        // 0..1
    const float4 yv = *(const float4*)(y + (size_t)sent * DD + c4 * 4);
    float* w0 = outp + (size_t)sent * SENT_STRIDE + (size_t)(q * 32 + rr) * DD + c4 * 4;
#pragma unroll
    for (int i = 0; i < 16; ++i)
        *(float4*)(w0 + (size_t)(i * 2) * DD) = yv;
}

extern "C" void kernel_launch(void* const* d_in, const int* in_sizes, int n_in,
                              void* d_out, int out_size, void* d_ws, size_t ws_size,
                              hipStream_t stream) {
    const float* x    = (const float*)d_in[0];
    const int*   mask = (const int*)  d_in[1];
    // d_in[2]=Wq, d_in[3]=bq dead (token softmax over singleton); d_in[5]=bk shift-invariant
    const float* Wk   = (const float*)d_in[4];
    const float* Wv   = (const float*)d_in[6];
    const float* bv   = (const float*)d_in[7];
    const float* sq   = (const float*)d_in[8];
    const float* Wo   = (const float*)d_in[9];
    const float* bo   = (const float*)d_in[10];
    float* out = (float*)d_out;
    float* ws  = (float*)d_ws;

    float* wk_t = ws + WK_OFF;
    float* w    = ws + W_OFF;
    float* xbar = ws + XB_OFF;
    float* z    = ws + Z_OFF;
    float* y    = ws + YY_OFF;

    precompute_wk<<<HH, DD, 0, stream>>>(Wk, sq, wk_t);
    ks_scores<<<NTOK / 8, 256, 0, stream>>>(x, mask, wk_t, w);
    kx_xbar<<<NSENT * 4, 128, 0, stream>>>(x, w, xbar);
    gemm_tile<<<256, 256, 0, stream>>>(xbar, HH * DD, DD, Wv, bv, z);
    gemm_tile<<<256, 256, 0, stream>>>(z, DD, 0, Wo, bo, y);
    kb_bcast<<<NSENT * 4, 256, 0, stream>>>(y, out);
}